// Round 1
// baseline (3728.674 us; speedup 1.0000x reference)
//
#include <hip/hip_runtime.h>
#include <hip/hip_bf16.h>

typedef __attribute__((ext_vector_type(8))) short bf16x8;
typedef __attribute__((ext_vector_type(4))) float f32x4;

// ---------- helpers ----------
__device__ __forceinline__ short f2bf(float f) {
    union { __hip_bfloat16 h; short s; } u;
    u.h = __float2bfloat16(f);
    return u.s;
}

__device__ __forceinline__ void gld_lds16(const void* g, void* l) {
    auto gp = (const __attribute__((address_space(1))) void*)(g);
    auto lp = (__attribute__((address_space(3))) void*)(l);
    __builtin_amdgcn_global_load_lds(gp, lp, 16, 0, 0);
}

// read a 16B bf16x8 fragment from a swizzled 64x128B LDS tile
__device__ __forceinline__ bf16x8 ldfrag(const char* base, int row, int k /*bf16 idx*/) {
    int off = (row << 7) + (((k << 1)) ^ ((row & 7) << 4));
    return *(const bf16x8*)(base + off);
}

// ---------- transpose + fp32->bf16 convert:  in[R][C] f32  ->  out[C][R] bf16 ----------
__global__ __launch_bounds__(256) void tcvt(const float* __restrict__ in,
                                            __hip_bfloat16* __restrict__ out,
                                            int R, int C) {
    __shared__ float tile[64][65];
    const int r0 = blockIdx.x << 6, c0 = blockIdx.y << 6;
    const int tid = threadIdx.x;
    const int tr = tid >> 4, tc4 = (tid & 15) << 2;
#pragma unroll
    for (int it = 0; it < 4; ++it) {
        int row = (it << 4) + tr;
        const float4 vv = *(const float4*)(in + (size_t)(r0 + row) * C + c0 + tc4);
        tile[row][tc4 + 0] = vv.x;
        tile[row][tc4 + 1] = vv.y;
        tile[row][tc4 + 2] = vv.z;
        tile[row][tc4 + 3] = vv.w;
    }
    __syncthreads();
#pragma unroll
    for (int it = 0; it < 4; ++it) {
        int row = (it << 4) + tr;  // row in C-dim of output
        short4 o;
        o.x = f2bf(tile[tc4 + 0][row]);
        o.y = f2bf(tile[tc4 + 1][row]);
        o.z = f2bf(tile[tc4 + 2][row]);
        o.w = f2bf(tile[tc4 + 3][row]);
        *(short4*)((short*)out + (size_t)(c0 + row) * R + r0 + tc4) = o;
    }
}

// ---------- elementwise fp32->bf16 (no transpose) ----------
__global__ __launch_bounds__(256) void cvt4(const float* __restrict__ in,
                                            __hip_bfloat16* __restrict__ out, int n4) {
    int i = blockIdx.x * 256 + threadIdx.x;
    if (i < n4) {
        float4 vv = ((const float4*)in)[i];
        short4 o;
        o.x = f2bf(vv.x); o.y = f2bf(vv.y); o.z = f2bf(vv.z); o.w = f2bf(vv.w);
        ((short4*)out)[i] = o;
    }
}

// ---------- tiled bf16 MFMA GEMM: C[M][N] = A[M][K] @ Bt[N][K]^T ----------
// MODE 0: h0 epilogue  (bf16 out, ld 4096)
// MODE 1: RNN step     (out = relu(acc + v0*Win0[c] + v1*Win1[c]) -> bf16 G_t)
// MODE 2: decoder      (fp32 out, row r -> t=r>>8, b=r&255, out[b][t][p])
template <int MODE>
__global__ __launch_bounds__(256) void gemm_k(const __hip_bfloat16* __restrict__ A,
                                              const __hip_bfloat16* __restrict__ B,
                                              int K, void* __restrict__ outp,
                                              const float* __restrict__ v,
                                              const float* __restrict__ Wi, int t) {
    __shared__ __align__(16) char lds[2][2][8192];  // [buf][A/B][64 rows x 128B], swizzled
    const int bm = blockIdx.x, bn = blockIdx.y;
    const int tid = threadIdx.x, wave = tid >> 6, lane = tid & 63;
    const int wr = wave >> 1, wc = wave & 1;

    const int nt = K >> 6;
    f32x4 acc[2][2] = {};

    auto stage = [&](int buf, int kt) {
        const int k0 = kt << 6;  // bf16 elems
#pragma unroll
        for (int iss = 0; iss < 2; ++iss) {
            int p = (wave << 11) + (iss << 10) + (lane << 4);  // byte offset in 8KB tile
            int row = p >> 7;
            int kb = p & 127;
            int kbs = kb ^ ((row & 7) << 4);  // inverse-swizzled source column
            const char* ga = (const char*)(A + (size_t)((bm << 6) + row) * K + k0) + kbs;
            const char* gb = (const char*)(B + (size_t)((bn << 6) + row) * K + k0) + kbs;
            gld_lds16(ga, &lds[buf][0][(wave << 11) + (iss << 10)]);
            gld_lds16(gb, &lds[buf][1][(wave << 11) + (iss << 10)]);
        }
    };

    stage(0, 0);
    __syncthreads();  // implicit vmcnt(0) drain before barrier
    int cur = 0;
    for (int kt = 0; kt < nt; ++kt) {
        if (kt + 1 < nt) stage(cur ^ 1, kt + 1);
        const char* Ab = (const char*)lds[cur][0];
        const char* Bb = (const char*)lds[cur][1];
#pragma unroll
        for (int kk = 0; kk < 64; kk += 32) {
            int kloc = kk + ((lane >> 4) << 3);
            bf16x8 a0 = ldfrag(Ab, (wr << 5) + (lane & 15), kloc);
            bf16x8 a1 = ldfrag(Ab, (wr << 5) + 16 + (lane & 15), kloc);
            bf16x8 b0 = ldfrag(Bb, (wc << 5) + (lane & 15), kloc);
            bf16x8 b1 = ldfrag(Bb, (wc << 5) + 16 + (lane & 15), kloc);
            acc[0][0] = __builtin_amdgcn_mfma_f32_16x16x32_bf16(a0, b0, acc[0][0], 0, 0, 0);
            acc[0][1] = __builtin_amdgcn_mfma_f32_16x16x32_bf16(a0, b1, acc[0][1], 0, 0, 0);
            acc[1][0] = __builtin_amdgcn_mfma_f32_16x16x32_bf16(a1, b0, acc[1][0], 0, 0, 0);
            acc[1][1] = __builtin_amdgcn_mfma_f32_16x16x32_bf16(a1, b1, acc[1][1], 0, 0, 0);
        }
        __syncthreads();
        cur ^= 1;
    }

    const int rb = (bm << 6) + (wr << 5) + ((lane >> 4) << 2);
    const int cb = (bn << 6) + (wc << 5) + (lane & 15);

    if constexpr (MODE == 0) {
        __hip_bfloat16* O = (__hip_bfloat16*)outp;  // h0 [256][4096]
#pragma unroll
        for (int mf = 0; mf < 2; ++mf)
#pragma unroll
            for (int j = 0; j < 4; ++j) {
                int r = rb + mf * 16 + j;
#pragma unroll
                for (int nf = 0; nf < 2; ++nf) {
                    int c = cb + nf * 16;
                    union { __hip_bfloat16 h; short s; } u;
                    u.s = f2bf(acc[mf][nf][j]);
                    O[(size_t)r * 4096 + c] = u.h;
                }
            }
    } else if constexpr (MODE == 1) {
        __hip_bfloat16* O = (__hip_bfloat16*)outp;  // G_t [256][4096]
#pragma unroll
        for (int mf = 0; mf < 2; ++mf)
#pragma unroll
            for (int j = 0; j < 4; ++j) {
                int b = rb + mf * 16 + j;
                float v0 = v[(size_t)(b * 100 + t) * 2 + 0];
                float v1 = v[(size_t)(b * 100 + t) * 2 + 1];
#pragma unroll
                for (int nf = 0; nf < 2; ++nf) {
                    int c = cb + nf * 16;
                    float x = v0 * Wi[c] + v1 * Wi[4096 + c];
                    float val = fmaxf(acc[mf][nf][j] + x, 0.0f);
                    union { __hip_bfloat16 h; short s; } u;
                    u.s = f2bf(val);
                    O[(size_t)b * 4096 + c] = u.h;
                }
            }
    } else {
        float* O = (float*)outp;  // place_preds [256][100][512]
#pragma unroll
        for (int mf = 0; mf < 2; ++mf)
#pragma unroll
            for (int j = 0; j < 4; ++j) {
                int r = rb + mf * 16 + j;
                int tt = r >> 8;
                int b = r & 255;
#pragma unroll
                for (int nf = 0; nf < 2; ++nf) {
                    int c = cb + nf * 16;
                    O[((size_t)b * 100 + tt) * 512 + c] = acc[mf][nf][j];
                }
            }
    }
}

// ---------- launch ----------
extern "C" void kernel_launch(void* const* d_in, const int* in_sizes, int n_in,
                              void* d_out, int out_size, void* d_ws, size_t ws_size,
                              hipStream_t stream) {
    const float* v     = (const float*)d_in[0];  // [256][100][2]
    const float* P0    = (const float*)d_in[1];  // [256][512]
    const float* W_enc = (const float*)d_in[2];  // [512][4096]
    const float* W_in  = (const float*)d_in[3];  // [2][4096]
    const float* W_rec = (const float*)d_in[4];  // [4096][4096]
    const float* W_dec = (const float*)d_in[5];  // [4096][512]
    float* out = (float*)d_out;                  // [256][100][512]

    char* ws = (char*)d_ws;
    __hip_bfloat16* Wrt = (__hip_bfloat16*)(ws + 0);          // [4096][4096] = W_rec^T
    __hip_bfloat16* Wet = (__hip_bfloat16*)(ws + 33554432);   // [4096][512]  = W_enc^T
    __hip_bfloat16* Wdt = (__hip_bfloat16*)(ws + 37748736);   // [512][4096]  = W_dec^T
    __hip_bfloat16* P0b = (__hip_bfloat16*)(ws + 41943040);   // [256][512]
    __hip_bfloat16* h0  = (__hip_bfloat16*)(ws + 42205184);   // [256][4096]
    __hip_bfloat16* G   = (__hip_bfloat16*)(ws + 44302336);   // [100][256][4096]

    tcvt<<<dim3(64, 64), 256, 0, stream>>>(W_rec, Wrt, 4096, 4096);
    tcvt<<<dim3(8, 64), 256, 0, stream>>>(W_enc, Wet, 512, 4096);
    tcvt<<<dim3(64, 8), 256, 0, stream>>>(W_dec, Wdt, 4096, 512);
    cvt4<<<128, 256, 0, stream>>>(P0, P0b, 32768);

    // h0 = P0 @ W_enc
    gemm_k<0><<<dim3(4, 64), 256, 0, stream>>>(P0b, Wet, 512, (void*)h0, nullptr, nullptr, 0);

    // recurrent steps
    for (int t = 0; t < 100; ++t) {
        const __hip_bfloat16* hprev = (t == 0) ? h0 : (G + (size_t)(t - 1) * 1048576);
        gemm_k<1><<<dim3(4, 64), 256, 0, stream>>>(hprev, Wrt, 4096,
                                                   (void*)(G + (size_t)t * 1048576), v, W_in, t);
    }

    // decoder: [25600,4096] @ Wdt^T -> d_out
    gemm_k<2><<<dim3(400, 8), 256, 0, stream>>>(G, Wdt, 4096, (void*)out, nullptr, nullptr, 0);
}

// Round 2
// 1932.619 us; speedup vs baseline: 1.9293x; 1.9293x over previous
//
#include <hip/hip_runtime.h>
#include <hip/hip_bf16.h>

typedef __attribute__((ext_vector_type(8))) short bf16x8;
typedef __attribute__((ext_vector_type(4))) float f32x4;

// ---------- helpers ----------
__device__ __forceinline__ short f2bf(float f) {
    union { __hip_bfloat16 h; short s; } u;
    u.h = __float2bfloat16(f);
    return u.s;
}

__device__ __forceinline__ void gld_lds16(const void* g, void* l) {
    auto gp = (const __attribute__((address_space(1))) void*)(g);
    auto lp = (__attribute__((address_space(3))) void*)(l);
    __builtin_amdgcn_global_load_lds(gp, lp, 16, 0, 0);
}

// read a 16B bf16x8 fragment from a swizzled 64x128B LDS tile
__device__ __forceinline__ bf16x8 ldfrag(const char* base, int row, int k /*bf16 idx*/) {
    int off = (row << 7) + (((k << 1)) ^ ((row & 7) << 4));
    return *(const bf16x8*)(base + off);
}

// ---------- transpose + fp32->bf16 convert:  in[R][C] f32  ->  out[C][R] bf16 ----------
__global__ __launch_bounds__(256) void tcvt(const float* __restrict__ in,
                                            __hip_bfloat16* __restrict__ out,
                                            int R, int C) {
    __shared__ float tile[64][65];
    const int r0 = blockIdx.x << 6, c0 = blockIdx.y << 6;
    const int tid = threadIdx.x;
    const int tr = tid >> 4, tc4 = (tid & 15) << 2;
#pragma unroll
    for (int it = 0; it < 4; ++it) {
        int row = (it << 4) + tr;
        const float4 vv = *(const float4*)(in + (size_t)(r0 + row) * C + c0 + tc4);
        tile[row][tc4 + 0] = vv.x;
        tile[row][tc4 + 1] = vv.y;
        tile[row][tc4 + 2] = vv.z;
        tile[row][tc4 + 3] = vv.w;
    }
    __syncthreads();
#pragma unroll
    for (int it = 0; it < 4; ++it) {
        int row = (it << 4) + tr;  // row in C-dim of output
        short4 o;
        o.x = f2bf(tile[tc4 + 0][row]);
        o.y = f2bf(tile[tc4 + 1][row]);
        o.z = f2bf(tile[tc4 + 2][row]);
        o.w = f2bf(tile[tc4 + 3][row]);
        *(short4*)((short*)out + (size_t)(c0 + row) * R + r0 + tc4) = o;
    }
}

// ---------- elementwise fp32->bf16 (no transpose) ----------
__global__ __launch_bounds__(256) void cvt4(const float* __restrict__ in,
                                            __hip_bfloat16* __restrict__ out, int n4) {
    int i = blockIdx.x * 256 + threadIdx.x;
    if (i < n4) {
        float4 vv = ((const float4*)in)[i];
        short4 o;
        o.x = f2bf(vv.x); o.y = f2bf(vv.y); o.z = f2bf(vv.z); o.w = f2bf(vv.w);
        ((short4*)out)[i] = o;
    }
}

// ---------- tiled bf16 MFMA GEMM: C[M][N] = A[M][K] @ Bt[N][K]^T ----------
// Depth-3 prefetch pipeline, 4 LDS buffers, counted vmcnt (never 0 in main loop).
// MODE 0: h0 epilogue  (bf16 out, ld 4096)
// MODE 1: RNN step     (out = relu(acc + v0*Win0[c] + v1*Win1[c]) -> bf16 G_t)
// MODE 2: decoder      (fp32 out, row r -> t=r>>8, b=r&255, out[b][t][p])
template <int MODE>
__global__ __launch_bounds__(256) void gemm_k(const __hip_bfloat16* __restrict__ A,
                                              const __hip_bfloat16* __restrict__ B,
                                              int K, void* __restrict__ outp,
                                              const float* __restrict__ v,
                                              const float* __restrict__ Wi, int t) {
    __shared__ __align__(16) char lds[4][2][8192];  // [buf][A/B][64 rows x 128B], swizzled
    const int id = blockIdx.x;
    int bm, bn;
    if constexpr (MODE == 2) {
        // 3200 blocks; chunk per XCD so the 8 bn-blocks sharing an A-slab stay on one XCD
        int xcd = id & 7, idx = id >> 3;
        int sw = xcd * 400 + idx;
        bm = sw >> 3;
        bn = sw & 7;
    } else {
        // 256 blocks; XCD k owns bn in [8k, 8k+8) -> W slab L2-resident across steps
        int xcd = id & 7, j = id >> 3;
        bn = (xcd << 3) + (j & 7);
        bm = j >> 3;
    }
    const int tid = threadIdx.x, wave = tid >> 6, lane = tid & 63;
    const int wr = wave >> 1, wc = wave & 1;

    const int nt = K >> 6;
    f32x4 acc[2][2] = {};

    auto stage = [&](int buf, int kt) {
        const int k0 = kt << 6;  // bf16 elems
#pragma unroll
        for (int iss = 0; iss < 2; ++iss) {
            int p = (wave << 11) + (iss << 10) + (lane << 4);  // byte offset in 8KB tile
            int row = p >> 7;
            int kb = p & 127;
            int kbs = kb ^ ((row & 7) << 4);  // inverse-swizzled source column
            const char* ga = (const char*)(A + (size_t)((bm << 6) + row) * K + k0) + kbs;
            const char* gb = (const char*)(B + (size_t)((bn << 6) + row) * K + k0) + kbs;
            gld_lds16(ga, &lds[buf][0][(wave << 11) + (iss << 10)]);
            gld_lds16(gb, &lds[buf][1][(wave << 11) + (iss << 10)]);
        }
    };

    auto do_iter = [&](int kt) {
        const char* Ab = (const char*)lds[kt & 3][0];
        const char* Bb = (const char*)lds[kt & 3][1];
        bf16x8 a0[2], a1[2], b0[2], b1[2];
#pragma unroll
        for (int h = 0; h < 2; ++h) {
            int kloc = (h << 5) + ((lane >> 4) << 3);
            a0[h] = ldfrag(Ab, (wr << 5) + (lane & 15), kloc);
            a1[h] = ldfrag(Ab, (wr << 5) + 16 + (lane & 15), kloc);
            b0[h] = ldfrag(Bb, (wc << 5) + (lane & 15), kloc);
            b1[h] = ldfrag(Bb, (wc << 5) + 16 + (lane & 15), kloc);
        }
        if (kt + 3 < nt) stage((kt + 3) & 3, kt + 3);
#pragma unroll
        for (int h = 0; h < 2; ++h) {
            acc[0][0] = __builtin_amdgcn_mfma_f32_16x16x32_bf16(a0[h], b0[h], acc[0][0], 0, 0, 0);
            acc[0][1] = __builtin_amdgcn_mfma_f32_16x16x32_bf16(a0[h], b1[h], acc[0][1], 0, 0, 0);
            acc[1][0] = __builtin_amdgcn_mfma_f32_16x16x32_bf16(a1[h], b0[h], acc[1][0], 0, 0, 0);
            acc[1][1] = __builtin_amdgcn_mfma_f32_16x16x32_bf16(a1[h], b1[h], acc[1][1], 0, 0, 0);
        }
    };

#define PIPE_ITER(KT, VM)                                           \
    do {                                                            \
        asm volatile("s_waitcnt vmcnt(" #VM ")" ::: "memory");      \
        __builtin_amdgcn_s_barrier();                               \
        do_iter(KT);                                                \
    } while (0)

    stage(0, 0);
    stage(1, 1);
    stage(2, 2);
    // steady state: 12 loads outstanding per wave (4 per buffer); wait to 8 -> oldest buf done
    for (int kt = 0; kt < nt - 2; ++kt) PIPE_ITER(kt, 8);
    PIPE_ITER(nt - 2, 4);
    PIPE_ITER(nt - 1, 0);
#undef PIPE_ITER

    const int rb = (bm << 6) + (wr << 5) + ((lane >> 4) << 2);
    const int cb = (bn << 6) + (wc << 5) + (lane & 15);

    if constexpr (MODE == 0) {
        __hip_bfloat16* O = (__hip_bfloat16*)outp;  // h0 [256][4096]
#pragma unroll
        for (int mf = 0; mf < 2; ++mf)
#pragma unroll
            for (int j = 0; j < 4; ++j) {
                int r = rb + mf * 16 + j;
#pragma unroll
                for (int nf = 0; nf < 2; ++nf) {
                    int c = cb + nf * 16;
                    union { __hip_bfloat16 h; short s; } u;
                    u.s = f2bf(acc[mf][nf][j]);
                    O[(size_t)r * 4096 + c] = u.h;
                }
            }
    } else if constexpr (MODE == 1) {
        __hip_bfloat16* O = (__hip_bfloat16*)outp;  // G_t [256][4096]
#pragma unroll
        for (int mf = 0; mf < 2; ++mf)
#pragma unroll
            for (int j = 0; j < 4; ++j) {
                int b = rb + mf * 16 + j;
                float v0 = v[(size_t)(b * 100 + t) * 2 + 0];
                float v1 = v[(size_t)(b * 100 + t) * 2 + 1];
#pragma unroll
                for (int nf = 0; nf < 2; ++nf) {
                    int c = cb + nf * 16;
                    float x = v0 * Wi[c] + v1 * Wi[4096 + c];
                    float val = fmaxf(acc[mf][nf][j] + x, 0.0f);
                    union { __hip_bfloat16 h; short s; } u;
                    u.s = f2bf(val);
                    O[(size_t)b * 4096 + c] = u.h;
                }
            }
    } else {
        float* O = (float*)outp;  // place_preds [256][100][512]
#pragma unroll
        for (int mf = 0; mf < 2; ++mf)
#pragma unroll
            for (int j = 0; j < 4; ++j) {
                int r = rb + mf * 16 + j;
                int tt = r >> 8;
                int b = r & 255;
#pragma unroll
                for (int nf = 0; nf < 2; ++nf) {
                    int c = cb + nf * 16;
                    O[((size_t)b * 100 + tt) * 512 + c] = acc[mf][nf][j];
                }
            }
    }
}

// ---------- launch ----------
extern "C" void kernel_launch(void* const* d_in, const int* in_sizes, int n_in,
                              void* d_out, int out_size, void* d_ws, size_t ws_size,
                              hipStream_t stream) {
    const float* v     = (const float*)d_in[0];  // [256][100][2]
    const float* P0    = (const float*)d_in[1];  // [256][512]
    const float* W_enc = (const float*)d_in[2];  // [512][4096]
    const float* W_in  = (const float*)d_in[3];  // [2][4096]
    const float* W_rec = (const float*)d_in[4];  // [4096][4096]
    const float* W_dec = (const float*)d_in[5];  // [4096][512]
    float* out = (float*)d_out;                  // [256][100][512]

    char* ws = (char*)d_ws;
    __hip_bfloat16* Wrt = (__hip_bfloat16*)(ws + 0);          // [4096][4096] = W_rec^T
    __hip_bfloat16* Wet = (__hip_bfloat16*)(ws + 33554432);   // [4096][512]  = W_enc^T
    __hip_bfloat16* Wdt = (__hip_bfloat16*)(ws + 37748736);   // [512][4096]  = W_dec^T
    __hip_bfloat16* P0b = (__hip_bfloat16*)(ws + 41943040);   // [256][512]
    __hip_bfloat16* h0  = (__hip_bfloat16*)(ws + 42205184);   // [256][4096]
    __hip_bfloat16* G   = (__hip_bfloat16*)(ws + 44302336);   // [100][256][4096]

    tcvt<<<dim3(64, 64), 256, 0, stream>>>(W_rec, Wrt, 4096, 4096);
    tcvt<<<dim3(8, 64), 256, 0, stream>>>(W_enc, Wet, 512, 4096);
    tcvt<<<dim3(64, 8), 256, 0, stream>>>(W_dec, Wdt, 4096, 512);
    cvt4<<<128, 256, 0, stream>>>(P0, P0b, 32768);

    // h0 = P0 @ W_enc
    gemm_k<0><<<256, 256, 0, stream>>>(P0b, Wet, 512, (void*)h0, nullptr, nullptr, 0);

    // recurrent steps
    for (int t = 0; t < 100; ++t) {
        const __hip_bfloat16* hprev = (t == 0) ? h0 : (G + (size_t)(t - 1) * 1048576);
        gemm_k<1><<<256, 256, 0, stream>>>(hprev, Wrt, 4096,
                                           (void*)(G + (size_t)t * 1048576), v, W_in, t);
    }

    // decoder: [25600,4096] @ Wdt^T -> d_out
    gemm_k<2><<<3200, 256, 0, stream>>>(G, Wdt, 4096, (void*)out, nullptr, nullptr, 0);
}